// Round 1
// 820.462 us; speedup vs baseline: 1.0504x; 1.0504x over previous
//
#include <hip/hip_runtime.h>

#define NCAM 6
#define DN   118
#define FHH  32
#define FWW  88
#define CCH  80
#define NXV  360
#define NYV  360
#define NXY  (NXV*NYV)
#define ACC_BYTES ((size_t)NXY * CCH * 4)   // 41,472,000

typedef float f32x4 __attribute__((ext_vector_type(4)));

// 3x3 inverse computed in f64, cast to f32 — mimics np.linalg.inv which
// promotes float32 -> float64 internally (_commonType) then casts back.
__device__ __forceinline__ void inv3_f64_to_f32(const float* a, float* inv) {
#pragma clang fp contract(off)
  double m00=a[0], m01=a[1], m02=a[2];
  double m10=a[3], m11=a[4], m12=a[5];
  double m20=a[6], m21=a[7], m22=a[8];
  double c00 = m11*m22 - m12*m21;
  double c01 = m10*m22 - m12*m20;
  double c02 = m10*m21 - m11*m20;
  double det = m00*c00 - m01*c01 + m02*c02;
  inv[0] = (float)( c00/det);
  inv[1] = (float)(-(m01*m22 - m02*m21)/det);
  inv[2] = (float)( (m01*m12 - m02*m11)/det);
  inv[3] = (float)(-c01/det);
  inv[4] = (float)( (m00*m22 - m02*m20)/det);
  inv[5] = (float)(-(m00*m12 - m02*m10)/det);
  inv[6] = (float)( c02/det);
  inv[7] = (float)(-(m00*m21 - m01*m20)/det);
  inv[8] = (float)( (m00*m11 - m01*m10)/det);
}

// Per-camera matrices: mats[n*24 + ...]
//   [0..8]  inv(post_rots)   (f32)
//   [9..17] combine = c2l_rots @ inv(intrins)  (f32 SOP, numpy einsum order)
//   [18..20] c2l_trans
//   [21..23] post_trans
__global__ void setup_mats_kernel(const float* __restrict__ c2l_rots,
                                  const float* __restrict__ c2l_trans,
                                  const float* __restrict__ intrins,
                                  const float* __restrict__ post_rots,
                                  const float* __restrict__ post_trans,
                                  float* __restrict__ mats) {
#pragma clang fp contract(off)
  int n = threadIdx.x;
  if (n >= NCAM) return;
  float iPR[9], iK[9];
  inv3_f64_to_f32(post_rots + n*9, iPR);
  inv3_f64_to_f32(intrins  + n*9, iK);
  const float* R = c2l_rots + n*9;
  float* o = mats + n*24;
  for (int i = 0; i < 3; i++)
    for (int k = 0; k < 3; k++) {
      float s = R[i*3+0] * iK[0*3+k];      // sequential SOP, no fma:
      s = s + R[i*3+1] * iK[1*3+k];        // matches np.einsum optimize=False
      s = s + R[i*3+2] * iK[2*3+k];
      o[9 + i*3 + k] = s;
    }
  for (int i = 0; i < 9; i++) o[i] = iPR[i];
  for (int i = 0; i < 3; i++) { o[18+i] = c2l_trans[n*3+i]; o[21+i] = post_trans[n*3+i]; }
}

template<bool DIRECT>
__device__ __forceinline__ void flush_acc(float* dst, int bin, int c, const float4& a) {
  if (DIRECT) {
    atomicAdd(dst + (size_t)(c+0)*NXY + bin, a.x);
    atomicAdd(dst + (size_t)(c+1)*NXY + bin, a.y);
    atomicAdd(dst + (size_t)(c+2)*NXY + bin, a.z);
    atomicAdd(dst + (size_t)(c+3)*NXY + bin, a.w);
  } else {
    float* p = dst + (size_t)bin*CCH + c;
    atomicAdd(p+0, a.x); atomicAdd(p+1, a.y);
    atomicAdd(p+2, a.z); atomicAdd(p+3, a.w);
  }
}

// One block = one (n,d) pair x 8 consecutive w columns x all 32 h rows.
// Phase 1: 256 threads compute the voxel bin of each (w_local,h) point.
// Phase 2: 160 threads, each owns (w_local, 4 channels).
//   Fast path (bins uniform over kept h — exact for this geometry since
//   cx,cy are h-independent): branch-free fully-unrolled 32x float4 load
//   with cndmask-to-zero accumulation -> deep load pipelining, 1 flush.
//   Fallback: generic run-length reduce over h (old path, verbatim).
template<bool DIRECT>
__global__ __launch_bounds__(256) void scatter_kernel(
    const float* __restrict__ x,
    const float* __restrict__ mats,
    const float* __restrict__ extra_rots,
    const float* __restrict__ extra_trans,
    float* __restrict__ dst) {
#pragma clang fp contract(off)
  __shared__ int bins[256];
  const int b  = blockIdx.x;
  const int nd = b / (FWW/8);
  const int w0 = (b - nd*(FWW/8)) * 8;
  const int n  = nd / DN;
  const int d  = nd - n*DN;
  const int t  = threadIdx.x;

  {
    const int wl = t >> 5, h = t & 31;
    const int w  = w0 + wl;
    const float* M = mats + n*24;
    // frustum values: np.linspace computes in f64 then casts to f32
    float u   = (float)(((double)w * 703.0) / 87.0);
    float v   = (float)(((double)h * 255.0) / 31.0);
    float dep = 1.0f + 0.5f*(float)d;                  // exact
    // pts = frustum - post_trans
    float f0 = u - M[21], f1 = v - M[22], f2 = dep - M[23];
    // pts = inv(post_rots) @ pts   (SOP order j=0,1,2, no fma)
    float s;
    s = M[0]*f0; s = s + M[1]*f1; s = s + M[2]*f2; float g0 = s;
    s = M[3]*f0; s = s + M[4]*f1; s = s + M[5]*f2; float g1 = s;
    s = M[6]*f0; s = s + M[7]*f1; s = s + M[8]*f2; float g2 = s;
    // undo perspective
    float q0 = g0*g2, q1 = g1*g2, q2 = g2;
    // pts = combine @ q + c2l_trans
    s = M[ 9]*q0; s = s + M[10]*q1; s = s + M[11]*q2; float r0 = s + M[18];
    s = M[12]*q0; s = s + M[13]*q1; s = s + M[14]*q2; float r1 = s + M[19];
    s = M[15]*q0; s = s + M[16]*q1; s = s + M[17]*q2; float r2 = s + M[20];
    // pts = extra_rots @ pts + extra_trans
    s = extra_rots[0]*r0; s = s + extra_rots[1]*r1; s = s + extra_rots[2]*r2; float e0 = s + extra_trans[0];
    s = extra_rots[3]*r0; s = s + extra_rots[4]*r1; s = s + extra_rots[5]*r2; float e1 = s + extra_trans[1];
    s = extra_rots[6]*r0; s = s + extra_rots[7]*r1; s = s + extra_rots[8]*r2; float e2 = s + extra_trans[2];
    // voxelize; (BX - DX/2) in f32 == (-54, -54, -10) exactly
    const float bs01 = -53.85f - (0.3f*0.5f);
    const float bs2  =   0.0f  - (20.0f*0.5f);
    float fx = (e0 - bs01) / 0.3f;
    float fy = (e1 - bs01) / 0.3f;
    float fz = (e2 - bs2 ) / 20.0f;
    int cx = (int)fx, cy = (int)fy, cz = (int)fz;   // trunc toward zero = astype(int32)
    bool kept = (cx >= 0) & (cx < NXV) & (cy >= 0) & (cy < NYV) & (cz >= 0) & (cz < 1);
    bins[t] = kept ? ((cz*NXV + cx)*NYV + cy) : -1;
  }
  __syncthreads();

  if (t < 160) {
    const int wl = t / 20, c4 = (t - wl*20) * 4;
    const int w  = w0 + wl;
    const float* xb = x + (((size_t)nd*FHH*FWW + w) * CCH + c4);
    const int* bl = bins + (wl << 5);

    // Scan column: kept-mask, first bin, uniformity (LDS broadcast reads).
    unsigned mask = 0u;
    int bin0 = -1;
    bool uniform = true;
#pragma unroll
    for (int h = 0; h < FHH; h++) {
      int bi = bl[h];
      if (bi >= 0) {
        if (bin0 < 0)           bin0 = bi;
        else if (bi != bin0)    uniform = false;
        mask |= (1u << h);
      }
    }

    if (uniform) {
      if (mask != 0u) {
        float4 acc = make_float4(0.f, 0.f, 0.f, 0.f);
#pragma unroll
        for (int h = 0; h < FHH; h++) {
          const f32x4 v = __builtin_nontemporal_load(
              (const f32x4*)(xb + (size_t)h * (FWW*CCH)));
          const bool k = (mask >> h) & 1u;
          acc.x += k ? v.x : 0.0f;
          acc.y += k ? v.y : 0.0f;
          acc.z += k ? v.z : 0.0f;
          acc.w += k ? v.w : 0.0f;
        }
        flush_acc<DIRECT>(dst, bin0, c4, acc);
      }
    } else {
      // Generic run-length fallback (old path): correct for arbitrary geometry.
      float4 acc = make_float4(0.f, 0.f, 0.f, 0.f);
      int cur = -1;
      for (int h = 0; h < FHH; h++) {
        int bi = bl[h];
        if (bi != cur) {
          if (cur >= 0) flush_acc<DIRECT>(dst, cur, c4, acc);
          cur = bi;
          acc = make_float4(0.f, 0.f, 0.f, 0.f);
        }
        if (bi >= 0) {
          const float4 val = *(const float4*)(xb + (size_t)h * (FWW*CCH));
          acc.x += val.x; acc.y += val.y; acc.z += val.z; acc.w += val.w;
        }
      }
      if (cur >= 0) flush_acc<DIRECT>(dst, cur, c4, acc);
    }
  }
}

// accum[xy][c] -> out[c][xy], 64-row tiles through padded LDS
__global__ __launch_bounds__(256) void transpose_kernel(const float* __restrict__ accum,
                                                        float* __restrict__ out) {
  __shared__ float tile[64*81];
  const int xy0 = blockIdx.x * 64;
  const int t = threadIdx.x;
  for (int i = t; i < 64*CCH; i += 256) {
    int r = i / CCH, c = i - r*CCH;
    tile[r*81 + c] = accum[(size_t)(xy0 + r)*CCH + c];
  }
  __syncthreads();
  for (int i = t; i < 64*CCH; i += 256) {
    int c = i >> 6, r = i & 63;
    out[(size_t)c*NXY + xy0 + r] = tile[r*81 + c];
  }
}

extern "C" void kernel_launch(void* const* d_in, const int* in_sizes, int n_in,
                              void* d_out, int out_size, void* d_ws, size_t ws_size,
                              hipStream_t stream) {
  const float* x           = (const float*)d_in[0];
  const float* c2l_rots    = (const float*)d_in[1];
  const float* c2l_trans   = (const float*)d_in[2];
  const float* intrins     = (const float*)d_in[3];
  const float* post_rots   = (const float*)d_in[4];
  const float* post_trans  = (const float*)d_in[5];
  const float* extra_rots  = (const float*)d_in[6];
  const float* extra_trans = (const float*)d_in[7];
  float* out = (float*)d_out;
  const int nblocks = NCAM * DN * (FWW/8);   // 7788

  if (ws_size >= ACC_BYTES + 1024) {
    float* accum = (float*)d_ws;
    float* mats  = (float*)((char*)d_ws + ACC_BYTES);
    hipMemsetAsync(accum, 0, ACC_BYTES, stream);
    setup_mats_kernel<<<1, 64, 0, stream>>>(c2l_rots, c2l_trans, intrins,
                                            post_rots, post_trans, mats);
    scatter_kernel<false><<<nblocks, 256, 0, stream>>>(x, mats, extra_rots,
                                                       extra_trans, accum);
    transpose_kernel<<<NXY/64, 256, 0, stream>>>(accum, out);
  } else {
    // fallback: atomics straight into d_out ([c][xy] layout), no transpose
    float* mats = (float*)d_ws;
    hipMemsetAsync(out, 0, (size_t)out_size * 4, stream);
    setup_mats_kernel<<<1, 64, 0, stream>>>(c2l_rots, c2l_trans, intrins,
                                            post_rots, post_trans, mats);
    scatter_kernel<true><<<nblocks, 256, 0, stream>>>(x, mats, extra_rots,
                                                      extra_trans, out);
  }
}

// Round 2
// 817.718 us; speedup vs baseline: 1.0539x; 1.0034x over previous
//
#include <hip/hip_runtime.h>

#define NCAM 6
#define DN   118
#define FHH  32
#define FWW  88
#define CCH  80
#define NXV  360
#define NYV  360
#define NXY  (NXV*NYV)
#define ACC_BYTES ((size_t)NXY * CCH * 4)   // 41,472,000

typedef float f32x4 __attribute__((ext_vector_type(4)));

// 3x3 inverse computed in f64, cast to f32 — mimics np.linalg.inv which
// promotes float32 -> float64 internally (_commonType) then casts back.
__device__ __forceinline__ void inv3_f64_to_f32(const float* a, float* inv) {
#pragma clang fp contract(off)
  double m00=a[0], m01=a[1], m02=a[2];
  double m10=a[3], m11=a[4], m12=a[5];
  double m20=a[6], m21=a[7], m22=a[8];
  double c00 = m11*m22 - m12*m21;
  double c01 = m10*m22 - m12*m20;
  double c02 = m10*m21 - m11*m20;
  double det = m00*c00 - m01*c01 + m02*c02;
  inv[0] = (float)( c00/det);
  inv[1] = (float)(-(m01*m22 - m02*m21)/det);
  inv[2] = (float)( (m01*m12 - m02*m11)/det);
  inv[3] = (float)(-c01/det);
  inv[4] = (float)( (m00*m22 - m02*m20)/det);
  inv[5] = (float)(-(m00*m12 - m02*m10)/det);
  inv[6] = (float)( c02/det);
  inv[7] = (float)(-(m00*m21 - m01*m20)/det);
  inv[8] = (float)( (m00*m11 - m01*m10)/det);
}

// Per-camera matrices: mats[n*24 + ...]
//   [0..8]  inv(post_rots)   (f32)
//   [9..17] combine = c2l_rots @ inv(intrins)  (f32 SOP, numpy einsum order)
//   [18..20] c2l_trans
//   [21..23] post_trans
__global__ void setup_mats_kernel(const float* __restrict__ c2l_rots,
                                  const float* __restrict__ c2l_trans,
                                  const float* __restrict__ intrins,
                                  const float* __restrict__ post_rots,
                                  const float* __restrict__ post_trans,
                                  float* __restrict__ mats) {
#pragma clang fp contract(off)
  int n = threadIdx.x;
  if (n >= NCAM) return;
  float iPR[9], iK[9];
  inv3_f64_to_f32(post_rots + n*9, iPR);
  inv3_f64_to_f32(intrins  + n*9, iK);
  const float* R = c2l_rots + n*9;
  float* o = mats + n*24;
  for (int i = 0; i < 3; i++)
    for (int k = 0; k < 3; k++) {
      float s = R[i*3+0] * iK[0*3+k];      // sequential SOP, no fma:
      s = s + R[i*3+1] * iK[1*3+k];        // matches np.einsum optimize=False
      s = s + R[i*3+2] * iK[2*3+k];
      o[9 + i*3 + k] = s;
    }
  for (int i = 0; i < 9; i++) o[i] = iPR[i];
  for (int i = 0; i < 3; i++) { o[18+i] = c2l_trans[n*3+i]; o[21+i] = post_trans[n*3+i]; }
}

template<bool DIRECT>
__device__ __forceinline__ void flush_acc(float* dst, int bin, int c, const float4& a) {
  if (DIRECT) {
    atomicAdd(dst + (size_t)(c+0)*NXY + bin, a.x);
    atomicAdd(dst + (size_t)(c+1)*NXY + bin, a.y);
    atomicAdd(dst + (size_t)(c+2)*NXY + bin, a.z);
    atomicAdd(dst + (size_t)(c+3)*NXY + bin, a.w);
  } else {
    float* p = dst + (size_t)bin*CCH + c;
    atomicAdd(p+0, a.x); atomicAdd(p+1, a.y);
    atomicAdd(p+2, a.z); atomicAdd(p+3, a.w);
  }
}

// One block = one (n,d) pair x 8 consecutive w columns x all 32 h rows.
// Phase 1: 256 threads compute the voxel bin of each (w_local,h) point.
// Phase 2: 160 threads, each owns (w_local, 4 channels).
//   Fast path (bins uniform over kept h — exact for this geometry since
//   cx,cy are h-independent):
//     - whole-column skip when mask==0 (saves ~10% of x fetch: d>~106)
//     - all 32 float4 loads staged into an explicit register array first
//       (forces 32 loads in flight before the first vmcnt wait), then a
//       branch-free cndmask accumulate, then exactly 1 flush.
//   Fallback: generic run-length reduce over h (old path, verbatim).
template<bool DIRECT>
__global__ __launch_bounds__(256) void scatter_kernel(
    const float* __restrict__ x,
    const float* __restrict__ mats,
    const float* __restrict__ extra_rots,
    const float* __restrict__ extra_trans,
    float* __restrict__ dst) {
#pragma clang fp contract(off)
  __shared__ int bins[256];
  const int b  = blockIdx.x;
  const int nd = b / (FWW/8);
  const int w0 = (b - nd*(FWW/8)) * 8;
  const int n  = nd / DN;
  const int d  = nd - n*DN;
  const int t  = threadIdx.x;

  {
    const int wl = t >> 5, h = t & 31;
    const int w  = w0 + wl;
    const float* M = mats + n*24;
    // frustum values: np.linspace computes in f64 then casts to f32
    float u   = (float)(((double)w * 703.0) / 87.0);
    float v   = (float)(((double)h * 255.0) / 31.0);
    float dep = 1.0f + 0.5f*(float)d;                  // exact
    // pts = frustum - post_trans
    float f0 = u - M[21], f1 = v - M[22], f2 = dep - M[23];
    // pts = inv(post_rots) @ pts   (SOP order j=0,1,2, no fma)
    float s;
    s = M[0]*f0; s = s + M[1]*f1; s = s + M[2]*f2; float g0 = s;
    s = M[3]*f0; s = s + M[4]*f1; s = s + M[5]*f2; float g1 = s;
    s = M[6]*f0; s = s + M[7]*f1; s = s + M[8]*f2; float g2 = s;
    // undo perspective
    float q0 = g0*g2, q1 = g1*g2, q2 = g2;
    // pts = combine @ q + c2l_trans
    s = M[ 9]*q0; s = s + M[10]*q1; s = s + M[11]*q2; float r0 = s + M[18];
    s = M[12]*q0; s = s + M[13]*q1; s = s + M[14]*q2; float r1 = s + M[19];
    s = M[15]*q0; s = s + M[16]*q1; s = s + M[17]*q2; float r2 = s + M[20];
    // pts = extra_rots @ pts + extra_trans
    s = extra_rots[0]*r0; s = s + extra_rots[1]*r1; s = s + extra_rots[2]*r2; float e0 = s + extra_trans[0];
    s = extra_rots[3]*r0; s = s + extra_rots[4]*r1; s = s + extra_rots[5]*r2; float e1 = s + extra_trans[1];
    s = extra_rots[6]*r0; s = s + extra_rots[7]*r1; s = s + extra_rots[8]*r2; float e2 = s + extra_trans[2];
    // voxelize; (BX - DX/2) in f32 == (-54, -54, -10) exactly
    const float bs01 = -53.85f - (0.3f*0.5f);
    const float bs2  =   0.0f  - (20.0f*0.5f);
    float fx = (e0 - bs01) / 0.3f;
    float fy = (e1 - bs01) / 0.3f;
    float fz = (e2 - bs2 ) / 20.0f;
    int cx = (int)fx, cy = (int)fy, cz = (int)fz;   // trunc toward zero = astype(int32)
    bool kept = (cx >= 0) & (cx < NXV) & (cy >= 0) & (cy < NYV) & (cz >= 0) & (cz < 1);
    bins[t] = kept ? ((cz*NXV + cx)*NYV + cy) : -1;
  }
  __syncthreads();

  if (t < 160) {
    const int wl = t / 20, c4 = (t - wl*20) * 4;
    const int w  = w0 + wl;
    const float* xb = x + (((size_t)nd*FHH*FWW + w) * CCH + c4);
    const int* bl = bins + (wl << 5);

    // Scan column: kept-mask, first bin, uniformity (LDS broadcast reads).
    unsigned mask = 0u;
    int bin0 = -1;
    bool uniform = true;
#pragma unroll
    for (int h = 0; h < FHH; h++) {
      int bi = bl[h];
      if (bi >= 0) {
        if (bin0 < 0)           bin0 = bi;
        else if (bi != bin0)    uniform = false;
        mask |= (1u << h);
      }
    }

    if (uniform) {
      if (mask != 0u) {
        // Stage all 32 rows into registers first: 32 independent 16B loads
        // in flight before any vmcnt wait (static indices only).
        f32x4 v[FHH];
#pragma unroll
        for (int h = 0; h < FHH; h++)
          v[h] = __builtin_nontemporal_load(
              (const f32x4*)(xb + (size_t)h * (FWW*CCH)));
        float4 acc = make_float4(0.f, 0.f, 0.f, 0.f);
#pragma unroll
        for (int h = 0; h < FHH; h++) {
          const bool k = (mask >> h) & 1u;
          acc.x += k ? v[h].x : 0.0f;
          acc.y += k ? v[h].y : 0.0f;
          acc.z += k ? v[h].z : 0.0f;
          acc.w += k ? v[h].w : 0.0f;
        }
        flush_acc<DIRECT>(dst, bin0, c4, acc);
      }
    } else {
      // Generic run-length fallback (old path): correct for arbitrary geometry.
      float4 acc = make_float4(0.f, 0.f, 0.f, 0.f);
      int cur = -1;
      for (int h = 0; h < FHH; h++) {
        int bi = bl[h];
        if (bi != cur) {
          if (cur >= 0) flush_acc<DIRECT>(dst, cur, c4, acc);
          cur = bi;
          acc = make_float4(0.f, 0.f, 0.f, 0.f);
        }
        if (bi >= 0) {
          const float4 val = *(const float4*)(xb + (size_t)h * (FWW*CCH));
          acc.x += val.x; acc.y += val.y; acc.z += val.z; acc.w += val.w;
        }
      }
      if (cur >= 0) flush_acc<DIRECT>(dst, cur, c4, acc);
    }
  }
}

// accum[xy][c] -> out[c][xy], 64-row tiles through padded LDS
__global__ __launch_bounds__(256) void transpose_kernel(const float* __restrict__ accum,
                                                        float* __restrict__ out) {
  __shared__ float tile[64*81];
  const int xy0 = blockIdx.x * 64;
  const int t = threadIdx.x;
  for (int i = t; i < 64*CCH; i += 256) {
    int r = i / CCH, c = i - r*CCH;
    tile[r*81 + c] = accum[(size_t)(xy0 + r)*CCH + c];
  }
  __syncthreads();
  for (int i = t; i < 64*CCH; i += 256) {
    int c = i >> 6, r = i & 63;
    out[(size_t)c*NXY + xy0 + r] = tile[r*81 + c];
  }
}

extern "C" void kernel_launch(void* const* d_in, const int* in_sizes, int n_in,
                              void* d_out, int out_size, void* d_ws, size_t ws_size,
                              hipStream_t stream) {
  const float* x           = (const float*)d_in[0];
  const float* c2l_rots    = (const float*)d_in[1];
  const float* c2l_trans   = (const float*)d_in[2];
  const float* intrins     = (const float*)d_in[3];
  const float* post_rots   = (const float*)d_in[4];
  const float* post_trans  = (const float*)d_in[5];
  const float* extra_rots  = (const float*)d_in[6];
  const float* extra_trans = (const float*)d_in[7];
  float* out = (float*)d_out;
  const int nblocks = NCAM * DN * (FWW/8);   // 7788

  if (ws_size >= ACC_BYTES + 1024) {
    float* accum = (float*)d_ws;
    float* mats  = (float*)((char*)d_ws + ACC_BYTES);
    hipMemsetAsync(accum, 0, ACC_BYTES, stream);
    setup_mats_kernel<<<1, 64, 0, stream>>>(c2l_rots, c2l_trans, intrins,
                                            post_rots, post_trans, mats);
    scatter_kernel<false><<<nblocks, 256, 0, stream>>>(x, mats, extra_rots,
                                                       extra_trans, accum);
    transpose_kernel<<<NXY/64, 256, 0, stream>>>(accum, out);
  } else {
    // fallback: atomics straight into d_out ([c][xy] layout), no transpose
    float* mats = (float*)d_ws;
    hipMemsetAsync(out, 0, (size_t)out_size * 4, stream);
    setup_mats_kernel<<<1, 64, 0, stream>>>(c2l_rots, c2l_trans, intrins,
                                            post_rots, post_trans, mats);
    scatter_kernel<true><<<nblocks, 256, 0, stream>>>(x, mats, extra_rots,
                                                      extra_trans, out);
  }
}